// Round 1
// baseline (250.059 us; speedup 1.0000x reference)
//
#include <hip/hip_runtime.h>
#include <stdint.h>

typedef __attribute__((ext_vector_type(8))) short bf16x8;
typedef __attribute__((ext_vector_type(4))) float f32x4;

constexpr int kOBS = 256;
constexpr int kSEQ = 2048;   // 1 + 2047
constexpr int kD   = 256;
constexpr int kHD  = 32;
constexpr int kFF  = 1024;
constexpr int kACH = 512;
constexpr int kA   = 16;

__device__ __forceinline__ unsigned short f2b(float f) {
  union { float f; unsigned int u; } v; v.f = f;
  unsigned int r = v.u + 0x7FFFu + ((v.u >> 16) & 1u);
  return (unsigned short)(r >> 16);
}

// ---------------------------------------------------------------- convert
// fp32 (K x N) -> bf16 transposed (N x K), 64x64 tiles via LDS.
struct ConvTable {
  const float* src[14];
  int K[14];
  int N[14];
  int dst[14];     // elem offset into wT
  int tstart[15];
};

__global__ __launch_bounds__(256) void k_convert(ConvTable tab,
                                                 unsigned short* __restrict__ wT) {
  __shared__ unsigned short lt[64][72];
  int b = blockIdx.x;
  int m = 0;
  while (b >= tab.tstart[m + 1]) m++;
  const int tloc = b - tab.tstart[m];
  const int N = tab.N[m], K = tab.K[m];
  const int ntile = N >> 6;
  const int k0 = (tloc / ntile) * 64, n0 = (tloc % ntile) * 64;
  const float* src = tab.src[m];
  const int tid = threadIdx.x;
  {
    const int r = tid >> 2, c16 = (tid & 3) * 16;
    const float* sp = src + (size_t)(k0 + r) * N + n0 + c16;
    #pragma unroll
    for (int j = 0; j < 16; j++) lt[r][c16 + j] = f2b(sp[j]);
  }
  __syncthreads();
  {
    const int n = tid >> 2, kc = (tid & 3) * 16;
    unsigned short* dp = wT + tab.dst[m] + (size_t)(n0 + n) * K + k0 + kc;
    unsigned short g[16];
    #pragma unroll
    for (int j = 0; j < 16; j++) g[j] = lt[kc + j][n];
    *(bf16x8*)dp = *(bf16x8*)&g[0];
    *(bf16x8*)(dp + 8) = *(bf16x8*)&g[8];
  }
}

// ---------------------------------------------------------------- row 0 embed
__global__ __launch_bounds__(256) void k_row0(const float* __restrict__ obs,
                                              const float* __restrict__ Wc,
                                              const float* __restrict__ bc,
                                              float* __restrict__ xf,
                                              unsigned short* __restrict__ xb) {
  const int n = threadIdx.x;
  float a = bc[n];
  #pragma unroll 8
  for (int k = 0; k < kOBS; k++) a += obs[k] * Wc[k * kD + n];
  xf[n] = a;
  xb[n] = f2b(a);
}

// ---------------------------------------------------------------- GEMM 64x64
// C(M x N) = A(M x K) @ BT(N x K)^T ; bf16 MFMA 16x16x32, fp32 accum.
// EPI 0: memo  (+b_memo[n] + rowbias[r*D+n], store f32+bf16 at row r+1)
// EPI 1: qkv   (+bias, split cols 0..255/256..511/512..767 -> q,k,v bf16)
// EPI 2: gelu  (+bias, tanh-gelu, store bf16, row stride kFF)
// EPI 3: resid (+bias + resid(o1), store f32 to o0)
template <int EPI, bool AF32>
__global__ __launch_bounds__(256) void k_gemmA(
    const void* __restrict__ Ap, int lda, int M, int K,
    const unsigned short* __restrict__ BT,
    const float* __restrict__ p0, const float* __restrict__ p1,
    const float* __restrict__ p2,
    void* __restrict__ o0, void* __restrict__ o1, void* __restrict__ o2) {
  __shared__ unsigned short Al[64][40];
  __shared__ unsigned short Bl[64][40];
  const int tid = threadIdx.x;
  const int w = tid >> 6, l = tid & 63, lg = l >> 4, lr = l & 15;
  const int m0 = blockIdx.x * 64, n0 = blockIdx.y * 64;
  const int sr = tid >> 2, sk = (tid & 3) * 8;
  f32x4 acc[4];
  #pragma unroll
  for (int c = 0; c < 4; c++)
    #pragma unroll
    for (int i = 0; i < 4; i++) acc[c][i] = 0.f;

  for (int k0 = 0; k0 < K; k0 += 32) {
    __syncthreads();
    bf16x8 av;
    if (m0 + sr < M) {
      if constexpr (AF32) {
        const float* ap = (const float*)Ap + (size_t)(m0 + sr) * lda + k0 + sk;
        #pragma unroll
        for (int j = 0; j < 8; j++) av[j] = (short)f2b(ap[j]);
      } else {
        av = *(const bf16x8*)((const unsigned short*)Ap +
                              (size_t)(m0 + sr) * lda + k0 + sk);
      }
    } else {
      #pragma unroll
      for (int j = 0; j < 8; j++) av[j] = 0;
    }
    *(bf16x8*)&Al[sr][sk] = av;
    *(bf16x8*)&Bl[sr][sk] =
        *(const bf16x8*)(BT + (size_t)(n0 + sr) * K + k0 + sk);
    __syncthreads();
    bf16x8 af = *(bf16x8*)&Al[w * 16 + lr][8 * lg];
    #pragma unroll
    for (int c = 0; c < 4; c++) {
      bf16x8 bf = *(bf16x8*)&Bl[c * 16 + lr][8 * lg];
      acc[c] = __builtin_amdgcn_mfma_f32_16x16x32_bf16(af, bf, acc[c], 0, 0, 0);
    }
  }

  #pragma unroll
  for (int c = 0; c < 4; c++) {
    #pragma unroll
    for (int i = 0; i < 4; i++) {
      const int gr = m0 + w * 16 + 4 * lg + i;
      const int gc = n0 + c * 16 + lr;
      if (gr >= M) continue;
      float v = acc[c][i];
      if constexpr (EPI == 0) {
        v += p0[gc] + p1[(size_t)gr * kD + gc];
        ((float*)o0)[(size_t)(gr + 1) * kD + gc] = v;
        ((unsigned short*)o1)[(size_t)(gr + 1) * kD + gc] = f2b(v);
      } else if constexpr (EPI == 1) {
        const int t = gc >> 8, cc = gc & 255;
        const float* bp = (t == 0) ? p0 : (t == 1 ? p1 : p2);
        unsigned short* op = (t == 0) ? (unsigned short*)o0
                              : (t == 1 ? (unsigned short*)o1
                                        : (unsigned short*)o2);
        op[(size_t)gr * kD + cc] = f2b(v + bp[cc]);
      } else if constexpr (EPI == 2) {
        v += p0[gc];
        const float g =
            0.5f * v *
            (1.0f + tanhf(0.7978845608028654f * (v + 0.044715f * v * v * v)));
        ((unsigned short*)o0)[(size_t)gr * kFF + gc] = f2b(g);
      } else {
        v += p0[gc] + ((const float*)o1)[(size_t)gr * kD + gc];
        ((float*)o0)[(size_t)gr * kD + gc] = v;
      }
    }
  }
}

// ---------------------------------------------------------------- LayerNorm
// one row per wave, 4 rows per block
__global__ __launch_bounds__(256) void k_ln(const float* __restrict__ tin,
                                            const float* __restrict__ gam,
                                            const float* __restrict__ bet,
                                            float* __restrict__ xf,
                                            unsigned short* __restrict__ xb) {
  const int w = threadIdx.x >> 6, l = threadIdx.x & 63;
  const int row = blockIdx.x * 4 + w;
  f32x4 v = *(const f32x4*)(tin + (size_t)row * kD + l * 4);
  float s = v[0] + v[1] + v[2] + v[3];
  #pragma unroll
  for (int mm = 1; mm < 64; mm <<= 1) s += __shfl_xor(s, mm);
  const float mn = s * (1.0f / 256.0f);
  const float d0 = v[0] - mn, d1 = v[1] - mn, d2 = v[2] - mn, d3 = v[3] - mn;
  float s2 = d0 * d0 + d1 * d1 + d2 * d2 + d3 * d3;
  #pragma unroll
  for (int mm = 1; mm < 64; mm <<= 1) s2 += __shfl_xor(s2, mm);
  const float rstd = rsqrtf(s2 * (1.0f / 256.0f) + 1e-5f);
  f32x4 g4 = *(const f32x4*)(gam + l * 4);
  f32x4 b4 = *(const f32x4*)(bet + l * 4);
  f32x4 y;
  y[0] = d0 * rstd * g4[0] + b4[0];
  y[1] = d1 * rstd * g4[1] + b4[1];
  y[2] = d2 * rstd * g4[2] + b4[2];
  y[3] = d3 * rstd * g4[3] + b4[3];
  *(f32x4*)(xf + (size_t)row * kD + l * 4) = y;
  unsigned long long pk = (unsigned long long)f2b(y[0]) |
                          ((unsigned long long)f2b(y[1]) << 16) |
                          ((unsigned long long)f2b(y[2]) << 32) |
                          ((unsigned long long)f2b(y[3]) << 48);
  *(unsigned long long*)(xb + (size_t)row * kD + l * 4) = pk;
}

// ---------------------------------------------------------------- attention
// grid (32 q-blocks, 8 heads); block 256 thr = 4 waves x 16 q-rows.
// flash: online softmax over 32 kv-tiles of 64 keys.
__global__ __launch_bounds__(256) void k_attn(const unsigned short* __restrict__ q,
                                              const unsigned short* __restrict__ k,
                                              const unsigned short* __restrict__ v,
                                              unsigned short* __restrict__ ctx) {
  __shared__ unsigned short Kl[64][40];
  __shared__ unsigned short Vt[32][72];
  __shared__ unsigned short Pl[4][16][72];
  const int tid = threadIdx.x;
  const int w = tid >> 6, l = tid & 63, lg = l >> 4, lr = l & 15;
  const int q0 = blockIdx.x * 64;
  const int hoff = blockIdx.y * kHD;
  const int sr = tid >> 2, sk = (tid & 3) * 8;

  const bf16x8 qf =
      *(const bf16x8*)(q + (size_t)(q0 + w * 16 + lr) * kD + hoff + 8 * lg);

  float m_[4], l_[4];
  f32x4 acc[2];
  #pragma unroll
  for (int i = 0; i < 4; i++) { m_[i] = -1e30f; l_[i] = 0.f; }
  #pragma unroll
  for (int dt = 0; dt < 2; dt++)
    #pragma unroll
    for (int i = 0; i < 4; i++) acc[dt][i] = 0.f;

  const float scale = 0.17677669529663687f;  // 1/sqrt(32)

  bf16x8 kreg = *(const bf16x8*)(k + (size_t)sr * kD + hoff + sk);
  bf16x8 vreg = *(const bf16x8*)(v + (size_t)sr * kD + hoff + sk);

  for (int kt = 0; kt < kSEQ; kt += 64) {
    __syncthreads();
    *(bf16x8*)&Kl[sr][sk] = kreg;
    #pragma unroll
    for (int j = 0; j < 8; j++) Vt[sk + j][sr] = (unsigned short)vreg[j];
    __syncthreads();
    if (kt + 64 < kSEQ) {  // prefetch next tile into regs (hides HBM latency)
      kreg = *(const bf16x8*)(k + (size_t)(kt + 64 + sr) * kD + hoff + sk);
      vreg = *(const bf16x8*)(v + (size_t)(kt + 64 + sr) * kD + hoff + sk);
    }
    f32x4 s[4];
    #pragma unroll
    for (int c = 0; c < 4; c++) {
      f32x4 z;
      #pragma unroll
      for (int i = 0; i < 4; i++) z[i] = 0.f;
      bf16x8 kf = *(bf16x8*)&Kl[c * 16 + lr][8 * lg];
      s[c] = __builtin_amdgcn_mfma_f32_16x16x32_bf16(qf, kf, z, 0, 0, 0);
      #pragma unroll
      for (int i = 0; i < 4; i++) s[c][i] *= scale;
    }
    float tm[4];
    #pragma unroll
    for (int i = 0; i < 4; i++)
      tm[i] = fmaxf(fmaxf(s[0][i], s[1][i]), fmaxf(s[2][i], s[3][i]));
    #pragma unroll
    for (int mm = 1; mm <= 8; mm <<= 1)
      #pragma unroll
      for (int i = 0; i < 4; i++) tm[i] = fmaxf(tm[i], __shfl_xor(tm[i], mm));
    float p[4][4], rs[4], corr[4];
    #pragma unroll
    for (int i = 0; i < 4; i++) {
      const float nm = fmaxf(m_[i], tm[i]);
      corr[i] = __expf(m_[i] - nm);
      m_[i] = nm;
      rs[i] = 0.f;
    }
    #pragma unroll
    for (int c = 0; c < 4; c++)
      #pragma unroll
      for (int i = 0; i < 4; i++) {
        p[c][i] = __expf(s[c][i] - m_[i]);
        rs[i] += p[c][i];
      }
    #pragma unroll
    for (int mm = 1; mm <= 8; mm <<= 1)
      #pragma unroll
      for (int i = 0; i < 4; i++) rs[i] += __shfl_xor(rs[i], mm);
    #pragma unroll
    for (int i = 0; i < 4; i++) {
      l_[i] = l_[i] * corr[i] + rs[i];
      acc[0][i] *= corr[i];
      acc[1][i] *= corr[i];
    }
    #pragma unroll
    for (int c = 0; c < 4; c++)
      #pragma unroll
      for (int i = 0; i < 4; i++)
        Pl[w][4 * lg + i][c * 16 + lr] = f2b(p[c][i]);
    __syncthreads();
    #pragma unroll
    for (int k2 = 0; k2 < 2; k2++) {
      bf16x8 pf = *(bf16x8*)&Pl[w][lr][k2 * 32 + 8 * lg];
      #pragma unroll
      for (int dt = 0; dt < 2; dt++) {
        bf16x8 vf = *(bf16x8*)&Vt[dt * 16 + lr][k2 * 32 + 8 * lg];
        acc[dt] = __builtin_amdgcn_mfma_f32_16x16x32_bf16(pf, vf, acc[dt], 0, 0, 0);
      }
    }
  }
  #pragma unroll
  for (int dt = 0; dt < 2; dt++)
    #pragma unroll
    for (int i = 0; i < 4; i++) {
      const int gr = q0 + w * 16 + 4 * lg + i;
      ctx[(size_t)gr * kD + hoff + dt * 16 + lr] = f2b(acc[dt][i] / l_[i]);
    }
}

// ---------------------------------------------------------------- heads
__global__ __launch_bounds__(256) void k_head1(const float* __restrict__ xf,
                                               const float* __restrict__ aW1,
                                               const float* __restrict__ ab1,
                                               const float* __restrict__ cW1,
                                               const float* __restrict__ cb1,
                                               float* __restrict__ h1) {
  __shared__ float tl[256];
  __shared__ float red[4][64];
  const int tid = threadIdx.x;
  tl[tid] = xf[tid];  // x row 0
  __syncthreads();
  const int jj = blockIdx.x * 64;
  const bool actor = jj < 512;
  const float* W = actor ? aW1 : cW1;
  const float* b = actor ? ab1 : cb1;
  const int j0 = actor ? jj : jj - 512;
  const int ks = tid >> 6, j = tid & 63;
  float s = 0.f;
  #pragma unroll 4
  for (int k2 = ks * 64; k2 < ks * 64 + 64; k2++)
    s += tl[k2] * W[(size_t)k2 * kACH + j0 + j];
  red[ks][j] = s;
  __syncthreads();
  if (tid < 64) {
    float t = red[0][tid] + red[1][tid] + red[2][tid] + red[3][tid] + b[j0 + tid];
    h1[jj + tid] = tanhf(t);
  }
}

__global__ __launch_bounds__(256) void k_head2(const float* __restrict__ h1,
                                               const float* __restrict__ aW2,
                                               const float* __restrict__ ab2,
                                               const float* __restrict__ cW2,
                                               const float* __restrict__ cb2,
                                               float* __restrict__ h2) {
  __shared__ float tl[512];
  __shared__ float red[4][64];
  const int tid = threadIdx.x;
  const int jj = blockIdx.x * 64;
  const bool actor = jj < 512;
  const float* hin = actor ? h1 : h1 + 512;
  tl[tid] = hin[tid];
  tl[tid + 256] = hin[tid + 256];
  __syncthreads();
  const float* W = actor ? aW2 : cW2;
  const float* b = actor ? ab2 : cb2;
  const int j0 = actor ? jj : jj - 512;
  const int ks = tid >> 6, j = tid & 63;
  float s = 0.f;
  #pragma unroll 4
  for (int k2 = ks * 128; k2 < ks * 128 + 128; k2++)
    s += tl[k2] * W[(size_t)k2 * kACH + j0 + j];
  red[ks][j] = s;
  __syncthreads();
  if (tid < 64) {
    float t = red[0][tid] + red[1][tid] + red[2][tid] + red[3][tid] + b[j0 + tid];
    h2[jj + tid] = tanhf(t);
  }
}

__global__ __launch_bounds__(256) void k_head3(const float* __restrict__ h2,
                                               const float* __restrict__ aWo,
                                               const float* __restrict__ abo,
                                               const float* __restrict__ cWo,
                                               const float* __restrict__ cbo,
                                               const float* __restrict__ obs,
                                               float* __restrict__ out) {
  __shared__ float ha[512], hc[512], vred[4];
  const int tid = threadIdx.x;
  ha[tid] = h2[tid];
  ha[tid + 256] = h2[tid + 256];
  hc[tid] = h2[512 + tid];
  hc[tid + 256] = h2[768 + tid];
  __syncthreads();
  // policy: 16 outputs x 16-thread groups
  const int g = tid >> 4, lane16 = tid & 15;
  float s = 0.f;
  for (int k2 = lane16 * 32; k2 < lane16 * 32 + 32; k2++)
    s += ha[k2] * aWo[(size_t)k2 * kA + g];
  #pragma unroll
  for (int mm = 1; mm <= 8; mm <<= 1) s += __shfl_xor(s, mm);
  if (lane16 == 0) out[1 + g] = s + abo[g];
  // value
  float vv = hc[tid] * cWo[tid] + hc[tid + 256] * cWo[tid + 256];
  #pragma unroll
  for (int mm = 1; mm <= 32; mm <<= 1) vv += __shfl_xor(vv, mm);
  if ((tid & 63) == 0) vred[tid >> 6] = vv;
  __syncthreads();
  if (tid == 0) out[0] = vred[0] + vred[1] + vred[2] + vred[3] + cbo[0];
  // new_vector
  out[17 + tid] = tanhf(obs[tid]);
}

// ---------------------------------------------------------------- launch
extern "C" void kernel_launch(void* const* d_in, const int* in_sizes, int n_in,
                              void* d_out, int out_size, void* d_ws, size_t ws_size,
                              hipStream_t stream) {
  const float* obs   = (const float*)d_in[0];
  const float* oldv  = (const float*)d_in[1];
  const float* Wcore = (const float*)d_in[2];
  const float* bcore = (const float*)d_in[3];
  const float* Wmemo = (const float*)d_in[4];
  const float* bmemo = (const float*)d_in[5];
  const float* Wq    = (const float*)d_in[6];
  const float* bq    = (const float*)d_in[7];
  const float* Wk    = (const float*)d_in[8];
  const float* bk    = (const float*)d_in[9];
  const float* Wv    = (const float*)d_in[10];
  const float* bv    = (const float*)d_in[11];
  const float* Wo    = (const float*)d_in[12];
  const float* bo    = (const float*)d_in[13];
  const float* ln1g  = (const float*)d_in[14];
  const float* ln1b  = (const float*)d_in[15];
  const float* ln2g  = (const float*)d_in[16];
  const float* ln2b  = (const float*)d_in[17];
  const float* Wff1  = (const float*)d_in[18];
  const float* bff1  = (const float*)d_in[19];
  const float* Wff2  = (const float*)d_in[20];
  const float* bff2  = (const float*)d_in[21];
  const float* aW1   = (const float*)d_in[22];
  const float* ab1   = (const float*)d_in[23];
  const float* aW2   = (const float*)d_in[24];
  const float* ab2   = (const float*)d_in[25];
  const float* aWo   = (const float*)d_in[26];
  const float* abo   = (const float*)d_in[27];
  const float* cW1   = (const float*)d_in[28];
  const float* cb1   = (const float*)d_in[29];
  const float* cW2   = (const float*)d_in[30];
  const float* cb2   = (const float*)d_in[31];
  const float* cWo   = (const float*)d_in[32];
  const float* cbo   = (const float*)d_in[33];

  char* ws = (char*)d_ws;
  float*          xf  = (float*)(ws + 0);                        // 2 MB
  unsigned short* xb  = (unsigned short*)(ws + (2u << 20));      // 1 MB
  unsigned short* qb  = (unsigned short*)(ws + (3u << 20));      // 1 MB
  unsigned short* kb  = (unsigned short*)(ws + (4u << 20));      // 1 MB
  unsigned short* vb  = (unsigned short*)(ws + (5u << 20));      // 1 MB
  unsigned short* ctb = (unsigned short*)(ws + (6u << 20));      // 1 MB
  unsigned short* hb  = (unsigned short*)(ws + (7u << 20));      // 4 MB
  float*          tmp = (float*)(ws + (11u << 20));              // 2 MB
  float*          h1  = (float*)(ws + (13u << 20));
  float*          h2  = (float*)(ws + (13u << 20) + 4096);
  unsigned short* wT  = (unsigned short*)(ws + (13u << 20) + 16384);

  const int oCore = 0, oMemo = 65536;
  int oQKV[2], oWoT[2], oFF1[2], oFF2[2];
  int cur = 131072;
  for (int l2 = 0; l2 < 2; l2++) {
    oQKV[l2] = cur; cur += 196608;
    oWoT[l2] = cur; cur += 65536;
    oFF1[l2] = cur; cur += 262144;
    oFF2[l2] = cur; cur += 262144;
  }

  ConvTable tab;
  int idx = 0, ts = 0;
  auto add = [&](const float* s, int K, int N, int dst) {
    tab.src[idx] = s; tab.K[idx] = K; tab.N[idx] = N; tab.dst[idx] = dst;
    tab.tstart[idx] = ts; ts += (K >> 6) * (N >> 6); idx++;
  };
  add(Wcore, 256, 256, oCore);
  add(Wmemo, 256, 256, oMemo);   // first OBS rows only
  for (int l2 = 0; l2 < 2; l2++) {
    add(Wq + l2 * 65536, 256, 256, oQKV[l2]);
    add(Wk + l2 * 65536, 256, 256, oQKV[l2] + 65536);
    add(Wv + l2 * 65536, 256, 256, oQKV[l2] + 131072);
    add(Wo + l2 * 65536, 256, 256, oWoT[l2]);
    add(Wff1 + l2 * 262144, 256, 1024, oFF1[l2]);
    add(Wff2 + l2 * 262144, 1024, 256, oFF2[l2]);
  }
  tab.tstart[14] = ts;

  k_row0<<<1, 256, 0, stream>>>(obs, Wcore, bcore, xf, xb);
  k_convert<<<ts, 256, 0, stream>>>(tab, wT);
  // memo embed: rows 1..2047, A = old_vectors (fp32, converted in staging)
  k_gemmA<0, true><<<dim3(32, 4), 256, 0, stream>>>(
      oldv, 256, 2047, 256, wT + oMemo, bmemo, Wmemo + 65536, nullptr,
      xf, xb, nullptr);

  for (int l2 = 0; l2 < 2; l2++) {
    k_gemmA<1, false><<<dim3(32, 12), 256, 0, stream>>>(
        xb, 256, 2048, 256, wT + oQKV[l2],
        bq + l2 * 256, bk + l2 * 256, bv + l2 * 256, qb, kb, vb);
    k_attn<<<dim3(32, 8), 256, 0, stream>>>(qb, kb, vb, ctb);
    k_gemmA<3, false><<<dim3(32, 4), 256, 0, stream>>>(
        ctb, 256, 2048, 256, wT + oWoT[l2],
        bo + l2 * 256, nullptr, nullptr, tmp, xf, nullptr);
    k_ln<<<512, 256, 0, stream>>>(tmp, ln1g + l2 * 256, ln1b + l2 * 256, xf, xb);
    k_gemmA<2, false><<<dim3(32, 16), 256, 0, stream>>>(
        xb, 256, 2048, 256, wT + oFF1[l2],
        bff1 + l2 * 1024, nullptr, nullptr, hb, nullptr, nullptr);
    k_gemmA<3, false><<<dim3(32, 4), 256, 0, stream>>>(
        hb, 1024, 2048, 1024, wT + oFF2[l2],
        bff2 + l2 * 256, nullptr, nullptr, tmp, xf, nullptr);
    k_ln<<<512, 256, 0, stream>>>(tmp, ln2g + l2 * 256, ln2b + l2 * 256, xf, xb);
  }

  k_head1<<<16, 256, 0, stream>>>(xf, aW1, ab1, cW1, cb1, h1);
  k_head2<<<16, 256, 0, stream>>>(h1, aW2, ab2, cW2, cb2, h2);
  k_head3<<<1, 256, 0, stream>>>(h2, aWo, abo, cWo, cbo, obs, (float*)d_out);
}

// Round 2
// 227.359 us; speedup vs baseline: 1.0998x; 1.0998x over previous
//
#include <hip/hip_runtime.h>
#include <stdint.h>

typedef __attribute__((ext_vector_type(8))) short bf16x8;
typedef __attribute__((ext_vector_type(4))) float f32x4;

constexpr int kOBS = 256;
constexpr int kSEQ = 2048;   // 1 + 2047
constexpr int kD   = 256;
constexpr int kHD  = 32;
constexpr int kFF  = 1024;
constexpr int kACH = 512;
constexpr int kA   = 16;

__device__ __forceinline__ unsigned short f2b(float f) {
  union { float f; unsigned int u; } v; v.f = f;
  unsigned int r = v.u + 0x7FFFu + ((v.u >> 16) & 1u);
  return (unsigned short)(r >> 16);
}

// ---------------------------------------------------------------- convert
// fp32 (K x N) -> bf16 transposed (N x K), 64x64 tiles via LDS.
struct ConvTable {
  const float* src[14];
  int K[14];
  int N[14];
  int dst[14];     // elem offset into wT
  int tstart[15];
};

__global__ __launch_bounds__(256) void k_convert(ConvTable tab,
                                                 unsigned short* __restrict__ wT) {
  __shared__ unsigned short lt[64][72];
  int b = blockIdx.x;
  int m = 0;
  while (b >= tab.tstart[m + 1]) m++;
  const int tloc = b - tab.tstart[m];
  const int N = tab.N[m], K = tab.K[m];
  const int ntile = N >> 6;
  const int k0 = (tloc / ntile) * 64, n0 = (tloc % ntile) * 64;
  const float* src = tab.src[m];
  const int tid = threadIdx.x;
  {
    const int r = tid >> 2, c16 = (tid & 3) * 16;
    const float* sp = src + (size_t)(k0 + r) * N + n0 + c16;
    #pragma unroll
    for (int j = 0; j < 16; j++) lt[r][c16 + j] = f2b(sp[j]);
  }
  __syncthreads();
  {
    const int n = tid >> 2, kc = (tid & 3) * 16;
    unsigned short* dp = wT + tab.dst[m] + (size_t)(n0 + n) * K + k0 + kc;
    unsigned short g[16];
    #pragma unroll
    for (int j = 0; j < 16; j++) g[j] = lt[kc + j][n];
    *(bf16x8*)dp = *(bf16x8*)&g[0];
    *(bf16x8*)(dp + 8) = *(bf16x8*)&g[8];
  }
}

// ---------------------------------------------------------------- row 0 embed
__global__ __launch_bounds__(256) void k_row0(const float* __restrict__ obs,
                                              const float* __restrict__ Wc,
                                              const float* __restrict__ bc,
                                              float* __restrict__ xf,
                                              unsigned short* __restrict__ xb) {
  const int n = threadIdx.x;
  float a = bc[n];
  #pragma unroll 8
  for (int k = 0; k < kOBS; k++) a += obs[k] * Wc[k * kD + n];
  xf[n] = a;
  xb[n] = f2b(a);
}

// ---------------------------------------------------------------- GEMM 64x64
// C(M x N) = A(M x K) @ BT(N x K)^T ; bf16 MFMA 16x16x32, fp32 accum.
// Register-prefetch double buffering: next k-step's global loads issue right
// after the barrier so L2 latency hides under the MFMAs.
// EPI 0: memo  (+b_memo[n] + rowbias[r*D+n], store f32+bf16 at row r+1)
// EPI 1: qkv   (+bias, q gets *1/sqrt(32) folded in; split cols -> q,k,v bf16)
// EPI 2: gelu  (+bias, tanh-gelu, store bf16, row stride kFF)
// EPI 3: resid (+bias + resid(o1), store f32 to o0)
template <int EPI, bool AF32>
__global__ __launch_bounds__(256) void k_gemmA(
    const void* __restrict__ Ap, int lda, int M, int K,
    const unsigned short* __restrict__ BT,
    const float* __restrict__ p0, const float* __restrict__ p1,
    const float* __restrict__ p2,
    void* __restrict__ o0, void* __restrict__ o1, void* __restrict__ o2) {
  __shared__ unsigned short Al[64][40];
  __shared__ unsigned short Bl[64][40];
  const int tid = threadIdx.x;
  const int w = tid >> 6, l = tid & 63, lg = l >> 4, lr = l & 15;
  const int m0 = blockIdx.x * 64, n0 = blockIdx.y * 64;
  const int sr = tid >> 2, sk = (tid & 3) * 8;
  f32x4 acc[4];
  #pragma unroll
  for (int c = 0; c < 4; c++)
    #pragma unroll
    for (int i = 0; i < 4; i++) acc[c][i] = 0.f;

  auto loadA = [&](int k0) -> bf16x8 {
    bf16x8 av;
    if (m0 + sr < M) {
      if constexpr (AF32) {
        const float* ap = (const float*)Ap + (size_t)(m0 + sr) * lda + k0 + sk;
        #pragma unroll
        for (int j = 0; j < 8; j++) av[j] = (short)f2b(ap[j]);
      } else {
        av = *(const bf16x8*)((const unsigned short*)Ap +
                              (size_t)(m0 + sr) * lda + k0 + sk);
      }
    } else {
      #pragma unroll
      for (int j = 0; j < 8; j++) av[j] = 0;
    }
    return av;
  };

  bf16x8 av = loadA(0);
  bf16x8 bv = *(const bf16x8*)(BT + (size_t)(n0 + sr) * K + sk);

  for (int k0 = 0; k0 < K; k0 += 32) {
    __syncthreads();
    *(bf16x8*)&Al[sr][sk] = av;
    *(bf16x8*)&Bl[sr][sk] = bv;
    __syncthreads();
    if (k0 + 32 < K) {
      av = loadA(k0 + 32);
      bv = *(const bf16x8*)(BT + (size_t)(n0 + sr) * K + k0 + 32 + sk);
    }
    bf16x8 af = *(bf16x8*)&Al[w * 16 + lr][8 * lg];
    #pragma unroll
    for (int c = 0; c < 4; c++) {
      bf16x8 bf = *(bf16x8*)&Bl[c * 16 + lr][8 * lg];
      acc[c] = __builtin_amdgcn_mfma_f32_16x16x32_bf16(af, bf, acc[c], 0, 0, 0);
    }
  }

  #pragma unroll
  for (int c = 0; c < 4; c++) {
    #pragma unroll
    for (int i = 0; i < 4; i++) {
      const int gr = m0 + w * 16 + 4 * lg + i;
      const int gc = n0 + c * 16 + lr;
      if (gr >= M) continue;
      float v = acc[c][i];
      if constexpr (EPI == 0) {
        v += p0[gc] + p1[(size_t)gr * kD + gc];
        ((float*)o0)[(size_t)(gr + 1) * kD + gc] = v;
        ((unsigned short*)o1)[(size_t)(gr + 1) * kD + gc] = f2b(v);
      } else if constexpr (EPI == 1) {
        const int t = gc >> 8, cc = gc & 255;
        const float* bp = (t == 0) ? p0 : (t == 1 ? p1 : p2);
        unsigned short* op = (t == 0) ? (unsigned short*)o0
                              : (t == 1 ? (unsigned short*)o1
                                        : (unsigned short*)o2);
        v += bp[cc];
        if (t == 0) v *= 0.17677669529663687f;  // 1/sqrt(32) folded into q
        op[(size_t)gr * kD + cc] = f2b(v);
      } else if constexpr (EPI == 2) {
        v += p0[gc];
        const float g =
            0.5f * v *
            (1.0f + tanhf(0.7978845608028654f * (v + 0.044715f * v * v * v)));
        ((unsigned short*)o0)[(size_t)gr * kFF + gc] = f2b(g);
      } else {
        v += p0[gc] + ((const float*)o1)[(size_t)gr * kD + gc];
        ((float*)o0)[(size_t)gr * kD + gc] = v;
      }
    }
  }
}

// ---------------------------------------------------------------- LayerNorm
__global__ __launch_bounds__(256) void k_ln(const float* __restrict__ tin,
                                            const float* __restrict__ gam,
                                            const float* __restrict__ bet,
                                            float* __restrict__ xf,
                                            unsigned short* __restrict__ xb) {
  const int w = threadIdx.x >> 6, l = threadIdx.x & 63;
  const int row = blockIdx.x * 4 + w;
  f32x4 v = *(const f32x4*)(tin + (size_t)row * kD + l * 4);
  float s = v[0] + v[1] + v[2] + v[3];
  #pragma unroll
  for (int mm = 1; mm < 64; mm <<= 1) s += __shfl_xor(s, mm);
  const float mn = s * (1.0f / 256.0f);
  const float d0 = v[0] - mn, d1 = v[1] - mn, d2 = v[2] - mn, d3 = v[3] - mn;
  float s2 = d0 * d0 + d1 * d1 + d2 * d2 + d3 * d3;
  #pragma unroll
  for (int mm = 1; mm < 64; mm <<= 1) s2 += __shfl_xor(s2, mm);
  const float rstd = rsqrtf(s2 * (1.0f / 256.0f) + 1e-5f);
  f32x4 g4 = *(const f32x4*)(gam + l * 4);
  f32x4 b4 = *(const f32x4*)(bet + l * 4);
  f32x4 y;
  y[0] = d0 * rstd * g4[0] + b4[0];
  y[1] = d1 * rstd * g4[1] + b4[1];
  y[2] = d2 * rstd * g4[2] + b4[2];
  y[3] = d3 * rstd * g4[3] + b4[3];
  *(f32x4*)(xf + (size_t)row * kD + l * 4) = y;
  unsigned long long pk = (unsigned long long)f2b(y[0]) |
                          ((unsigned long long)f2b(y[1]) << 16) |
                          ((unsigned long long)f2b(y[2]) << 32) |
                          ((unsigned long long)f2b(y[3]) << 48);
  *(unsigned long long*)(xb + (size_t)row * kD + l * 4) = pk;
}

// ---------------------------------------------------------------- attention
// Flash-decoding: grid (32 q-blocks, 8 heads, nsplit kv-splits).
// Each block covers tpb kv-tiles of 64 keys, writes unnormalized partials.
// Scale is pre-folded into q. Block 256 thr = 4 waves x 16 q-rows.
__global__ __launch_bounds__(256) void k_attn(const unsigned short* __restrict__ q,
                                              const unsigned short* __restrict__ k,
                                              const unsigned short* __restrict__ v,
                                              float* __restrict__ pacc,
                                              float* __restrict__ pml,
                                              int tpb) {
  __shared__ unsigned short Kl[64][40];
  __shared__ unsigned short Vt[32][72];
  __shared__ unsigned short Pl[4][16][72];
  const int tid = threadIdx.x;
  const int w = tid >> 6, l = tid & 63, lg = l >> 4, lr = l & 15;
  const int q0 = blockIdx.x * 64;
  const int hoff = blockIdx.y * kHD;
  const int sr = tid >> 2, sk = (tid & 3) * 8;
  const int t0 = blockIdx.z * tpb;

  const bf16x8 qf =
      *(const bf16x8*)(q + (size_t)(q0 + w * 16 + lr) * kD + hoff + 8 * lg);

  float m_[4], l_[4];
  f32x4 acc[2];
  #pragma unroll
  for (int i = 0; i < 4; i++) { m_[i] = -1e30f; l_[i] = 0.f; }
  #pragma unroll
  for (int dt = 0; dt < 2; dt++)
    #pragma unroll
    for (int i = 0; i < 4; i++) acc[dt][i] = 0.f;

  bf16x8 kreg = *(const bf16x8*)(k + (size_t)(t0 * 64 + sr) * kD + hoff + sk);
  bf16x8 vreg = *(const bf16x8*)(v + (size_t)(t0 * 64 + sr) * kD + hoff + sk);

  for (int t = 0; t < tpb; t++) {
    __syncthreads();
    *(bf16x8*)&Kl[sr][sk] = kreg;
    #pragma unroll
    for (int j = 0; j < 8; j++) Vt[sk + j][sr] = (unsigned short)vreg[j];
    __syncthreads();
    if (t + 1 < tpb) {
      const size_t nx = (size_t)((t0 + t + 1) * 64 + sr) * kD + hoff + sk;
      kreg = *(const bf16x8*)(k + nx);
      vreg = *(const bf16x8*)(v + nx);
    }
    f32x4 s[4];
    #pragma unroll
    for (int c = 0; c < 4; c++) {
      f32x4 z;
      #pragma unroll
      for (int i = 0; i < 4; i++) z[i] = 0.f;
      bf16x8 kf = *(bf16x8*)&Kl[c * 16 + lr][8 * lg];
      s[c] = __builtin_amdgcn_mfma_f32_16x16x32_bf16(qf, kf, z, 0, 0, 0);
    }
    float tm[4];
    #pragma unroll
    for (int i = 0; i < 4; i++)
      tm[i] = fmaxf(fmaxf(s[0][i], s[1][i]), fmaxf(s[2][i], s[3][i]));
    #pragma unroll
    for (int mm = 1; mm <= 8; mm <<= 1)
      #pragma unroll
      for (int i = 0; i < 4; i++) tm[i] = fmaxf(tm[i], __shfl_xor(tm[i], mm));
    float p[4][4], rs[4], corr[4];
    #pragma unroll
    for (int i = 0; i < 4; i++) {
      const float nm = fmaxf(m_[i], tm[i]);
      corr[i] = __expf(m_[i] - nm);
      m_[i] = nm;
      rs[i] = 0.f;
    }
    #pragma unroll
    for (int c = 0; c < 4; c++)
      #pragma unroll
      for (int i = 0; i < 4; i++) {
        p[c][i] = __expf(s[c][i] - m_[i]);
        rs[i] += p[c][i];
      }
    #pragma unroll
    for (int mm = 1; mm <= 8; mm <<= 1)
      #pragma unroll
      for (int i = 0; i < 4; i++) rs[i] += __shfl_xor(rs[i], mm);
    #pragma unroll
    for (int i = 0; i < 4; i++) {
      l_[i] = l_[i] * corr[i] + rs[i];
      acc[0][i] *= corr[i];
      acc[1][i] *= corr[i];
    }
    #pragma unroll
    for (int c = 0; c < 4; c++)
      #pragma unroll
      for (int i = 0; i < 4; i++)
        Pl[w][4 * lg + i][c * 16 + lr] = f2b(p[c][i]);
    __syncthreads();
    #pragma unroll
    for (int k2 = 0; k2 < 2; k2++) {
      bf16x8 pf = *(bf16x8*)&Pl[w][lr][k2 * 32 + 8 * lg];
      #pragma unroll
      for (int dt = 0; dt < 2; dt++) {
        bf16x8 vf = *(bf16x8*)&Vt[dt * 16 + lr][k2 * 32 + 8 * lg];
        acc[dt] = __builtin_amdgcn_mfma_f32_16x16x32_bf16(pf, vf, acc[dt], 0, 0, 0);
      }
    }
  }

  const int pb = blockIdx.z * 8 + blockIdx.y;
  float* pa = pacc + (size_t)pb * kSEQ * kHD;
  float* pm = pml + (size_t)pb * kSEQ * 2;
  #pragma unroll
  for (int dt = 0; dt < 2; dt++)
    #pragma unroll
    for (int i = 0; i < 4; i++) {
      const int gr = q0 + w * 16 + 4 * lg + i;
      pa[(size_t)gr * kHD + dt * 16 + lr] = acc[dt][i];
    }
  if (lr == 0) {
    #pragma unroll
    for (int i = 0; i < 4; i++) {
      const int gr = q0 + w * 16 + 4 * lg + i;
      float2 ml; ml.x = m_[i]; ml.y = l_[i];
      *(float2*)&pm[(size_t)gr * 2] = ml;
    }
  }
}

// ---------------------------------------------------------------- combine
// Merge nsplit partials per (head,row): out = sum_s acc_s*e^{m_s-M} / sum_s l_s*e^{m_s-M}
__global__ __launch_bounds__(256) void k_combine(const float* __restrict__ pacc,
                                                 const float* __restrict__ pml,
                                                 unsigned short* __restrict__ ctx,
                                                 int nsplit) {
  const int tid = threadIdx.x;
  const int d = tid & 31;
  const int g = blockIdx.x * 8 + (tid >> 5);   // g in [0, 8*2048)
  const int h = g >> 11;
  const int row = g & 2047;
  float M = -1e30f;
  for (int s = 0; s < nsplit; s++)
    M = fmaxf(M, pml[((size_t)(s * 8 + h) * kSEQ + row) * 2]);
  float L = 0.f, o = 0.f;
  for (int s = 0; s < nsplit; s++) {
    const size_t pb = (size_t)(s * 8 + h) * kSEQ + row;
    const float2 ml = *(const float2*)&pml[pb * 2];
    const float e = __expf(ml.x - M);
    L += ml.y * e;
    o += pacc[pb * kHD + d] * e;
  }
  ctx[(size_t)row * kD + h * kHD + d] = f2b(o / L);
}

// ---------------------------------------------------------------- heads
__global__ __launch_bounds__(256) void k_head1(const float* __restrict__ xf,
                                               const float* __restrict__ aW1,
                                               const float* __restrict__ ab1,
                                               const float* __restrict__ cW1,
                                               const float* __restrict__ cb1,
                                               float* __restrict__ h1) {
  __shared__ float tl[256];
  __shared__ float red[4][64];
  const int tid = threadIdx.x;
  tl[tid] = xf[tid];  // x row 0
  __syncthreads();
  const int jj = blockIdx.x * 64;
  const bool actor = jj < 512;
  const float* W = actor ? aW1 : cW1;
  const float* b = actor ? ab1 : cb1;
  const int j0 = actor ? jj : jj - 512;
  const int ks = tid >> 6, j = tid & 63;
  float s = 0.f;
  #pragma unroll 4
  for (int k2 = ks * 64; k2 < ks * 64 + 64; k2++)
    s += tl[k2] * W[(size_t)k2 * kACH + j0 + j];
  red[ks][j] = s;
  __syncthreads();
  if (tid < 64) {
    float t = red[0][tid] + red[1][tid] + red[2][tid] + red[3][tid] + b[j0 + tid];
    h1[jj + tid] = tanhf(t);
  }
}

__global__ __launch_bounds__(256) void k_head2(const float* __restrict__ h1,
                                               const float* __restrict__ aW2,
                                               const float* __restrict__ ab2,
                                               const float* __restrict__ cW2,
                                               const float* __restrict__ cb2,
                                               float* __restrict__ h2) {
  __shared__ float tl[512];
  __shared__ float red[4][64];
  const int tid = threadIdx.x;
  const int jj = blockIdx.x * 64;
  const bool actor = jj < 512;
  const float* hin = actor ? h1 : h1 + 512;
  tl[tid] = hin[tid];
  tl[tid + 256] = hin[tid + 256];
  __syncthreads();
  const float* W = actor ? aW2 : cW2;
  const float* b = actor ? ab2 : cb2;
  const int j0 = actor ? jj : jj - 512;
  const int ks = tid >> 6, j = tid & 63;
  float s = 0.f;
  #pragma unroll 4
  for (int k2 = ks * 128; k2 < ks * 128 + 128; k2++)
    s += tl[k2] * W[(size_t)k2 * kACH + j0 + j];
  red[ks][j] = s;
  __syncthreads();
  if (tid < 64) {
    float t = red[0][tid] + red[1][tid] + red[2][tid] + red[3][tid] + b[j0 + tid];
    h2[jj + tid] = tanhf(t);
  }
}

__global__ __launch_bounds__(256) void k_head3(const float* __restrict__ h2,
                                               const float* __restrict__ aWo,
                                               const float* __restrict__ abo,
                                               const float* __restrict__ cWo,
                                               const float* __restrict__ cbo,
                                               const float* __restrict__ obs,
                                               float* __restrict__ out) {
  __shared__ float ha[512], hc[512], vred[4];
  const int tid = threadIdx.x;
  ha[tid] = h2[tid];
  ha[tid + 256] = h2[tid + 256];
  hc[tid] = h2[512 + tid];
  hc[tid + 256] = h2[768 + tid];
  __syncthreads();
  const int g = tid >> 4, lane16 = tid & 15;
  float s = 0.f;
  for (int k2 = lane16 * 32; k2 < lane16 * 32 + 32; k2++)
    s += ha[k2] * aWo[(size_t)k2 * kA + g];
  #pragma unroll
  for (int mm = 1; mm <= 8; mm <<= 1) s += __shfl_xor(s, mm);
  if (lane16 == 0) out[1 + g] = s + abo[g];
  float vv = hc[tid] * cWo[tid] + hc[tid + 256] * cWo[tid + 256];
  #pragma unroll
  for (int mm = 1; mm <= 32; mm <<= 1) vv += __shfl_xor(vv, mm);
  if ((tid & 63) == 0) vred[tid >> 6] = vv;
  __syncthreads();
  if (tid == 0) out[0] = vred[0] + vred[1] + vred[2] + vred[3] + cbo[0];
  out[17 + tid] = tanhf(obs[tid]);
}

// ---------------------------------------------------------------- launch
extern "C" void kernel_launch(void* const* d_in, const int* in_sizes, int n_in,
                              void* d_out, int out_size, void* d_ws, size_t ws_size,
                              hipStream_t stream) {
  const float* obs   = (const float*)d_in[0];
  const float* oldv  = (const float*)d_in[1];
  const float* Wcore = (const float*)d_in[2];
  const float* bcore = (const float*)d_in[3];
  const float* Wmemo = (const float*)d_in[4];
  const float* bmemo = (const float*)d_in[5];
  const float* Wq    = (const float*)d_in[6];
  const float* bq    = (const float*)d_in[7];
  const float* Wk    = (const float*)d_in[8];
  const float* bk    = (const float*)d_in[9];
  const float* Wv    = (const float*)d_in[10];
  const float* bv    = (const float*)d_in[11];
  const float* Wo    = (const float*)d_in[12];
  const float* bo    = (const float*)d_in[13];
  const float* ln1g  = (const float*)d_in[14];
  const float* ln1b  = (const float*)d_in[15];
  const float* ln2g  = (const float*)d_in[16];
  const float* ln2b  = (const float*)d_in[17];
  const float* Wff1  = (const float*)d_in[18];
  const float* bff1  = (const float*)d_in[19];
  const float* Wff2  = (const float*)d_in[20];
  const float* bff2  = (const float*)d_in[21];
  const float* aW1   = (const float*)d_in[22];
  const float* ab1   = (const float*)d_in[23];
  const float* aW2   = (const float*)d_in[24];
  const float* ab2   = (const float*)d_in[25];
  const float* aWo   = (const float*)d_in[26];
  const float* abo   = (const float*)d_in[27];
  const float* cW1   = (const float*)d_in[28];
  const float* cb1   = (const float*)d_in[29];
  const float* cW2   = (const float*)d_in[30];
  const float* cb2   = (const float*)d_in[31];
  const float* cWo   = (const float*)d_in[32];
  const float* cbo   = (const float*)d_in[33];

  char* ws = (char*)d_ws;
  float*          xf  = (float*)(ws + 0);                        // 2 MB
  unsigned short* xb  = (unsigned short*)(ws + (2u << 20));      // 1 MB
  unsigned short* qb  = (unsigned short*)(ws + (3u << 20));      // 1 MB
  unsigned short* kb  = (unsigned short*)(ws + (4u << 20));      // 1 MB
  unsigned short* vb  = (unsigned short*)(ws + (5u << 20));      // 1 MB
  unsigned short* ctb = (unsigned short*)(ws + (6u << 20));      // 1 MB
  unsigned short* hb  = (unsigned short*)(ws + (7u << 20));      // 4 MB
  float*          tmp = (float*)(ws + (11u << 20));              // 2 MB
  float*          h1  = (float*)(ws + (13u << 20));
  float*          h2  = (float*)(ws + (13u << 20) + 4096);
  unsigned short* wT  = (unsigned short*)(ws + (13u << 20) + 16384);

  // flash-decoding partials, sized by ws_size (deterministic per harness)
  const size_t pacc_off = (size_t)17u << 20;
  int nsplit = 8;
  while (nsplit > 1 &&
         pacc_off + (size_t)nsplit * (8 * kSEQ * kHD * 4 + 8 * kSEQ * 2 * 4) >
             ws_size)
    nsplit >>= 1;
  float* pacc = (float*)(ws + pacc_off);
  float* pml  = (float*)(ws + pacc_off + (size_t)nsplit * 8 * kSEQ * kHD * 4);
  const int tpb = 32 / nsplit;

  const int oCore = 0, oMemo = 65536;
  int oQKV[2], oWoT[2], oFF1[2], oFF2[2];
  int cur = 131072;
  for (int l2 = 0; l2 < 2; l2++) {
    oQKV[l2] = cur; cur += 196608;
    oWoT[l2] = cur; cur += 65536;
    oFF1[l2] = cur; cur += 262144;
    oFF2[l2] = cur; cur += 262144;
  }

  ConvTable tab;
  int idx = 0, ts = 0;
  auto add = [&](const float* s, int K, int N, int dst) {
    tab.src[idx] = s; tab.K[idx] = K; tab.N[idx] = N; tab.dst[idx] = dst;
    tab.tstart[idx] = ts; ts += (K >> 6) * (N >> 6); idx++;
  };
  add(Wcore, 256, 256, oCore);
  add(Wmemo, 256, 256, oMemo);   // first OBS rows only
  for (int l2 = 0; l2 < 2; l2++) {
    add(Wq + l2 * 65536, 256, 256, oQKV[l2]);
    add(Wk + l2 * 65536, 256, 256, oQKV[l2] + 65536);
    add(Wv + l2 * 65536, 256, 256, oQKV[l2] + 131072);
    add(Wo + l2 * 65536, 256, 256, oWoT[l2]);
    add(Wff1 + l2 * 262144, 256, 1024, oFF1[l2]);
    add(Wff2 + l2 * 262144, 1024, 256, oFF2[l2]);
  }
  tab.tstart[14] = ts;

  k_row0<<<1, 256, 0, stream>>>(obs, Wcore, bcore, xf, xb);
  k_convert<<<ts, 256, 0, stream>>>(tab, wT);
  k_gemmA<0, true><<<dim3(32, 4), 256, 0, stream>>>(
      oldv, 256, 2047, 256, wT + oMemo, bmemo, Wmemo + 65536, nullptr,
      xf, xb, nullptr);

  for (int l2 = 0; l2 < 2; l2++) {
    k_gemmA<1, false><<<dim3(32, 12), 256, 0, stream>>>(
        xb, 256, 2048, 256, wT + oQKV[l2],
        bq + l2 * 256, bk + l2 * 256, bv + l2 * 256, qb, kb, vb);
    k_attn<<<dim3(32, 8, nsplit), 256, 0, stream>>>(qb, kb, vb, pacc, pml, tpb);
    k_combine<<<2048, 256, 0, stream>>>(pacc, pml, ctb, nsplit);
    k_gemmA<3, false><<<dim3(32, 4), 256, 0, stream>>>(
        ctb, 256, 2048, 256, wT + oWoT[l2],
        bo + l2 * 256, nullptr, nullptr, tmp, xf, nullptr);
    k_ln<<<512, 256, 0, stream>>>(tmp, ln1g + l2 * 256, ln1b + l2 * 256, xf, xb);
    k_gemmA<2, false><<<dim3(32, 16), 256, 0, stream>>>(
        xb, 256, 2048, 256, wT + oFF1[l2],
        bff1 + l2 * 1024, nullptr, nullptr, hb, nullptr, nullptr);
    k_gemmA<3, false><<<dim3(32, 4), 256, 0, stream>>>(
        hb, 1024, 2048, 1024, wT + oFF2[l2],
        bff2 + l2 * 256, nullptr, nullptr, tmp, xf, nullptr);
    k_ln<<<512, 256, 0, stream>>>(tmp, ln2g + l2 * 256, ln2b + l2 * 256, xf, xb);
  }

  k_head1<<<16, 256, 0, stream>>>(xf, aW1, ab1, cW1, cb1, h1);
  k_head2<<<16, 256, 0, stream>>>(h1, aW2, ab2, cW2, cb2, h2);
  k_head3<<<1, 256, 0, stream>>>(h2, aWo, abo, cWo, cbo, obs, (float*)d_out);
}